// Round 9
// baseline (101.037 us; speedup 1.0000x reference)
//
#include <hip/hip_runtime.h>

#define NQ 10
#define TS 10
#define DIM 1024
#define ND 1024
#define NR 16    // 16 complex amplitudes per lane

typedef float f2 __attribute__((ext_vector_type(2)));  // (re, im)

// ---------- hand-lowered VOP3P packed-f32 (compiler won't SLP-form these) ----
__device__ __forceinline__ f2 pk_mul(f2 a, f2 b) {
    f2 d;
    asm("v_pk_mul_f32 %0, %1, %2" : "=v"(d) : "v"(a), "v"(b));
    return d;
}
__device__ __forceinline__ f2 pk_fma(f2 a, f2 b, f2 c) {   // a*b + c
    f2 d;
    asm("v_pk_fma_f32 %0, %1, %2, %3" : "=v"(d) : "v"(a), "v"(b), "v"(c));
    return d;
}
__device__ __forceinline__ f2 pk_fma_sb(f2 a, f2 b, f2 c) { // a*b.yx + c (op_sel swap on src1)
    f2 d;
    asm("v_pk_fma_f32 %0, %1, %2, %3 op_sel:[0,1,0] op_sel_hi:[1,0,1]"
        : "=v"(d) : "v"(a), "v"(b), "v"(c));
    return d;
}

// ---------- full-rate cross-lane exchange via DPP ----------
template<int CTRL>
__device__ __forceinline__ float dpp_full(float x) {
    const int xi = __float_as_int(x);
    return __int_as_float(__builtin_amdgcn_update_dpp(xi, xi, CTRL, 0xF, 0xF, false));
}
__device__ __forceinline__ float dpp_xor4(float x) {
    const int xi = __float_as_int(x);
    // banks 0,2 (bit2=0) need src[i+4] -> row_shl:4 (0x104), bank_mask 0x5
    // banks 1,3 (bit2=1) need src[i-4] -> row_shr:4 (0x114), bank_mask 0xA
    int q = __builtin_amdgcn_update_dpp(0, xi, 0x104, 0xF, 0x5, false);
    q     = __builtin_amdgcn_update_dpp(q, xi, 0x114, 0xF, 0xA, false);
    return __int_as_float(q);
}
__device__ __forceinline__ float bperm(int addr, float x) {  // addr precomputed
    return __int_as_float(__builtin_amdgcn_ds_bpermute(addr, __float_as_int(x)));
}
template<int MASK>
__device__ __forceinline__ f2 xchg(f2 v, int addr) {
    if constexpr (MASK == 1)      return (f2){dpp_full<0xB1>(v.x),  dpp_full<0xB1>(v.y)};
    else if constexpr (MASK == 2) return (f2){dpp_full<0x4E>(v.x),  dpp_full<0x4E>(v.y)};
    else if constexpr (MASK == 4) return (f2){dpp_xor4(v.x),        dpp_xor4(v.y)};
    else if constexpr (MASK == 8) return (f2){dpp_full<0x128>(v.x), dpp_full<0x128>(v.y)};
    else                          return (f2){bperm(addr, v.x),     bperm(addr, v.y)};
}

// ---------- gates (M00=(A,-B) M01=(-C,-D) M10=(C,-D) M11=(A,B)) ----------
// In-thread pairing on register bit RB: 8 pk ops per pair (R7-verified formula).
template <int RB>
__device__ __forceinline__ void gate_r(f2* S, float A, float B, float C, float D) {
    const f2 AA = {A, A}, BN = {B, -B}, NB = {-B, B};
    const f2 CC = {C, C}, NC = {-C, -C}, DN = {D, -D};
#pragma unroll
    for (int r0 = 0; r0 < NR; ++r0) {
        if (r0 & (1 << RB)) continue;
        const int r1 = r0 | (1 << RB);
        const f2 x0 = S[r0], x1 = S[r1];
        S[r0] = pk_fma_sb(DN, x1, pk_fma(NC, x1, pk_fma_sb(BN, x0, pk_mul(AA, x0))));
        S[r1] = pk_fma_sb(NB, x1, pk_fma(AA, x1, pk_fma_sb(DN, x0, pk_mul(CC, x0))));
    }
}

// Cross-lane pairing on lane bit MASK: 4 pk + 2 exch per amp (R7-verified formula).
template <int MASK>
__device__ __forceinline__ void gate_lane(int lane, int addr, f2* S,
                                          float A, float B, float C, float D) {
    const float sgn = (lane & MASK) ? 1.f : -1.f;
    const float sB = sgn * B, sC = sgn * C;
    const f2 AA = {A, A}, SB = {-sB, sB}, SC = {sC, sC}, DN = {D, -D};
    f2 q[NR];
#pragma unroll
    for (int r = 0; r < NR; ++r) q[r] = xchg<MASK>(S[r], addr);  // batch exchanges
#pragma unroll
    for (int r = 0; r < NR; ++r) {
        const f2 o = S[r];
        S[r] = pk_fma_sb(DN, q[r], pk_fma(SC, q[r], pk_fma_sb(SB, o, pk_mul(AA, o))));
    }
}

// One wave per sample, full state in registers, zero LDS.
__global__ __launch_bounds__(64, 1) void qsim_kernel(
    const float* __restrict__ re_in, const float* __restrict__ im_in,
    const float* __restrict__ phis, const float* __restrict__ gs,
    float* __restrict__ out)
{
    const int sample = blockIdx.x;
    const int lane = threadIdx.x;

    const float* pr_in = re_in + sample * DIM;
    const float* pi_in = im_in + sample * DIM;

    f2 S[NR];
#pragma unroll
    for (int r = 0; r < NR; ++r) {
        S[r].x = pr_in[r * 64 + lane];
        S[r].y = pi_in[r * 64 + lane];
    }

    // precomputed bpermute addresses for xor16/xor32
    const int bp16 = ((lane ^ 16) << 2);
    const int bp32 = ((lane ^ 32) << 2);

    const float inv = 0.15811388300841897f;  // 1/(2*sqrt(10))
    float gl[TS];
#pragma unroll
    for (int t = 0; t < TS; ++t) gl[t] = gs[sample * TS + t] * inv;

    // ---- normalize ----
    f2 n2 = {0.f, 0.f};
#pragma unroll
    for (int r = 0; r < NR; ++r) n2 += S[r] * S[r];
    float nrm = n2.x + n2.y;
#pragma unroll
    for (int off = 32; off >= 1; off >>= 1) nrm += __shfl_xor(nrm, off, 64);
    const float scl = rsqrtf(nrm);
#pragma unroll
    for (int r = 0; r < NR; ++r) S[r] *= scl;

    // ---- pairsum per amplitude ----
    float ps[NR];
#pragma unroll
    for (int r = 0; r < NR; ++r) {
        const int idx = r * 64 + lane;
        const int z = NQ - 2 * __popc(idx);
        ps[r] = 0.5f * (float)(z * z - NQ);
    }

    const float* ph = phis + sample * (3 * NQ * TS);

    // software-pipelined uniform phi loads: phs = step tt, nxt = step tt+1
    float phs[30];
#pragma unroll
    for (int j = 0; j < 30; ++j) phs[j] = ph[j];

    for (int tt = 0; tt < TS; ++tt) {
        float nxt[30];
        if (tt + 1 < TS) {
#pragma unroll
            for (int j = 0; j < 30; ++j) nxt[j] = ph[30 * (tt + 1) + j];
        }

        // ---- all transcendentals for this step, hoisted & independent ----
        float GA[NQ], GB[NQ], GC[NQ], GD[NQ];
#pragma unroll
        for (int g = 0; g < NQ; ++g) {
            const float a = phs[g], th = phs[10 + g], b = phs[20 + g];
            float c, s, cp, sp, cm, sm;
            __sincosf(0.5f * th,      &s,  &c);
            __sincosf(0.5f * (a + b), &sp, &cp);
            __sincosf(0.5f * (a - b), &sm, &cm);
            GA[g] = c * cp; GB[g] = c * sp; GC[g] = s * cm; GD[g] = s * sm;
        }
        f2 EC[NR], ES[NR];
        const float kk = -0.5f * gl[tt];
#pragma unroll
        for (int r = 0; r < NR; ++r) {
            float sa, ca;
            __sincosf(kk * ps[r], &sa, &ca);
            EC[r] = (f2){ca, ca};
            ES[r] = (f2){-sa, sa};
        }

        // ---- gates: qubit q acts on idx bit (9-q) ----
        gate_r<3>(S, GA[0], GB[0], GC[0], GD[0]);                   // qubit 0 (bit 9)
        gate_r<2>(S, GA[1], GB[1], GC[1], GD[1]);                   // qubit 1 (bit 8)
        gate_r<1>(S, GA[2], GB[2], GC[2], GD[2]);                   // qubit 2 (bit 7)
        gate_r<0>(S, GA[3], GB[3], GC[3], GD[3]);                   // qubit 3 (bit 6)
        gate_lane<32>(lane, bp32, S, GA[4], GB[4], GC[4], GD[4]);   // qubit 4 (bperm)
        gate_lane<16>(lane, bp16, S, GA[5], GB[5], GC[5], GD[5]);   // qubit 5 (bperm)
        gate_lane< 8>(lane, 0,    S, GA[6], GB[6], GC[6], GD[6]);   // qubit 6 (DPP)
        gate_lane< 4>(lane, 0,    S, GA[7], GB[7], GC[7], GD[7]);   // qubit 7 (DPP)
        gate_lane< 2>(lane, 0,    S, GA[8], GB[8], GC[8], GD[8]);   // qubit 8 (DPP)
        gate_lane< 1>(lane, 0,    S, GA[9], GB[9], GC[9], GD[9]);   // qubit 9 (DPP)

        // ---- diagonal phase: S = EC*S + ES*S.yx ----
#pragma unroll
        for (int r = 0; r < NR; ++r) {
            S[r] = pk_fma_sb(ES[r], S[r], pk_mul(EC[r], S[r]));
        }

        if (tt + 1 < TS) {
#pragma unroll
            for (int j = 0; j < 30; ++j) phs[j] = nxt[j];
        }
    }

    float* outr = out + sample * DIM;
    float* outi = out + ND * DIM + sample * DIM;
#pragma unroll
    for (int r = 0; r < NR; ++r) {
        outr[r * 64 + lane] = S[r].x;
        outi[r * 64 + lane] = S[r].y;
    }
}

extern "C" void kernel_launch(void* const* d_in, const int* in_sizes, int n_in,
                              void* d_out, int out_size, void* d_ws, size_t ws_size,
                              hipStream_t stream) {
    const float* re_in = (const float*)d_in[0];
    const float* im_in = (const float*)d_in[1];
    const float* phis  = (const float*)d_in[2];
    const float* gs    = (const float*)d_in[3];
    float* out = (float*)d_out;
    qsim_kernel<<<ND, 64, 0, stream>>>(re_in, im_in, phis, gs, out);
}

// Round 10
// 92.541 us; speedup vs baseline: 1.0918x; 1.0918x over previous
//
#include <hip/hip_runtime.h>

#define NQ 10
#define TS 10
#define DIM 1024
#define ND 1024
#define NR 16    // 16 complex amplitudes per lane (Sr/Si float arrays)

// Circuit algebra: M = Rz(b)·Ry(th)·Rz(a); per-qubit factors commute across
// qubits, so each step = [Pi Rz(b_i)]·[Pi Ry_i]·[Pi Rz(a_i)]·D_pair, and all
// diagonals merge across step boundaries into ONE diagonal per boundary:
//   D(t): phi(idx) = sum_{set bits} v_i - 0.5*sum(v) + k*pairsum(idx),
//   v_i = a_i(t) + b_i(t-1)  (b(-1)=0),  k = -0.5*theta(t-1)  (0 for t=0).
// Ry is a REAL Givens rotation: 2 ops/float vs 4 for the fused complex gate.

// ---------- full-rate cross-lane exchange via DPP (verified R5) ----------
// row_shr:n -> dst[i]=src[i-n] (0x110|n); row_shl:n -> dst[i]=src[i+n] (0x100|n)
template<int CTRL>
__device__ __forceinline__ float dpp_full(float x) {
    const int xi = __float_as_int(x);
    return __int_as_float(__builtin_amdgcn_update_dpp(xi, xi, CTRL, 0xF, 0xF, false));
}
__device__ __forceinline__ float dpp_xor4(float x) {
    const int xi = __float_as_int(x);
    // banks 0,2 (bit2=0) need src[i+4] -> row_shl:4 (0x104), bank_mask 0x5
    // banks 1,3 (bit2=1) need src[i-4] -> row_shr:4 (0x114), bank_mask 0xA
    int q = __builtin_amdgcn_update_dpp(0, xi, 0x104, 0xF, 0x5, false);
    q     = __builtin_amdgcn_update_dpp(q, xi, 0x114, 0xF, 0xA, false);
    return __int_as_float(q);
}
template<int MASK>
__device__ __forceinline__ float lshuf(float x) {
    if constexpr (MASK == 1)      return dpp_full<0xB1>(x);   // quad_perm [1,0,3,2]
    else if constexpr (MASK == 2) return dpp_full<0x4E>(x);   // quad_perm [2,3,0,1]
    else if constexpr (MASK == 4) return dpp_xor4(x);
    else if constexpr (MASK == 8) return dpp_full<0x128>(x);  // row_ror:8 == xor8
    else return __shfl_xor(x, MASK, 64);                      // 16,32: ds_bpermute
}

// ---------- Ry gates (real rotation [[c,-s],[s,c]]) ----------
template <int RB>   // pairing on register bit RB
__device__ __forceinline__ void ry_r(float* Sr, float* Si, float c, float s) {
#pragma unroll
    for (int r0 = 0; r0 < NR; ++r0) {
        if (r0 & (1 << RB)) continue;
        const int r1 = r0 | (1 << RB);
        const float x0r = Sr[r0], x1r = Sr[r1];
        const float x0i = Si[r0], x1i = Si[r1];
        Sr[r0] = c * x0r - s * x1r;
        Sr[r1] = s * x0r + c * x1r;
        Si[r0] = c * x0i - s * x1i;
        Si[r1] = s * x0i + c * x1i;
    }
}
template <int MASK> // pairing on lane bit MASK
__device__ __forceinline__ void ry_lane(int lane, float* Sr, float* Si,
                                        float c, float s) {
    const float ss = (lane & MASK) ? s : -s;  // x' = c*own + ss*partner
    float qr[NR], qi[NR];
#pragma unroll
    for (int r = 0; r < NR; ++r) {
        qr[r] = lshuf<MASK>(Sr[r]);
        qi[r] = lshuf<MASK>(Si[r]);
    }
#pragma unroll
    for (int r = 0; r < NR; ++r) {
        Sr[r] = c * Sr[r] + ss * qr[r];
        Si[r] = c * Si[r] + ss * qi[r];
    }
}

// One wave per sample, full state in registers, zero LDS.
__global__ __launch_bounds__(64, 1) void qsim_kernel(
    const float* __restrict__ re_in, const float* __restrict__ im_in,
    const float* __restrict__ phis, const float* __restrict__ gs,
    float* __restrict__ out)
{
    const int sample = blockIdx.x;
    const int lane = threadIdx.x;

    const float* pr_in = re_in + sample * DIM;
    const float* pi_in = im_in + sample * DIM;

    float Sr[NR], Si[NR];
#pragma unroll
    for (int r = 0; r < NR; ++r) {
        Sr[r] = pr_in[r * 64 + lane];
        Si[r] = pi_in[r * 64 + lane];
    }

    const float inv = 0.15811388300841897f;  // 1/(2*sqrt(10))
    const float* gsp = gs + sample * TS;

    // ---- normalize ----
    float nrm = 0.f;
#pragma unroll
    for (int r = 0; r < NR; ++r) nrm += Sr[r] * Sr[r] + Si[r] * Si[r];
#pragma unroll
    for (int off = 32; off >= 1; off >>= 1) nrm += __shfl_xor(nrm, off, 64);
    const float scl = rsqrtf(nrm);
#pragma unroll
    for (int r = 0; r < NR; ++r) { Sr[r] *= scl; Si[r] *= scl; }

    // ---- static per-amp pairsum ----
    float ps[NR];
#pragma unroll
    for (int r = 0; r < NR; ++r) {
        const int idx = r * 64 + lane;
        const int z = NQ - 2 * __popc(idx);
        ps[r] = 0.5f * (float)(z * z - NQ);
    }
    // lane-bit indicators for qubits 4..9 (qubit 4+j <-> lane bit 5-j)
    float bl[6];
#pragma unroll
    for (int j = 0; j < 6; ++j) bl[j] = (float)((lane >> (5 - j)) & 1);

    const float* ph = phis + sample * (3 * NQ * TS);

    float bprev[NQ];
#pragma unroll
    for (int i = 0; i < NQ; ++i) bprev[i] = 0.f;
    float kk = 0.f;   // pair-diag coefficient from previous step

    // merged diagonal: phi[r] = (w_lane - 0.5*sum v + subset-sum v[0..3]) + kk*ps[r]
    auto apply_diag = [&](const float* v, float kcur) {
        float sv = 0.f;
#pragma unroll
        for (int i = 0; i < NQ; ++i) sv += v[i];
        float wl = 0.f;
#pragma unroll
        for (int j = 0; j < 6; ++j) wl = fmaf(bl[j], v[4 + j], wl);
        const float m = fmaf(-0.5f, sv, wl);
        // r bit3<->qubit0(v0), bit2<->qubit1(v1), bit1<->qubit2(v2), bit0<->qubit3(v3)
        const float Hm[4] = {m, m + v[1], m + v[0], m + v[0] + v[1]};
        const float L[4]  = {0.f, v[3], v[2], v[2] + v[3]};
#pragma unroll
        for (int r = 0; r < NR; ++r) {
            const float phi = fmaf(kcur, ps[r], Hm[r >> 2] + L[r & 3]);
            float sp, cp;
            __sincosf(phi, &sp, &cp);
            const float xr = Sr[r], xi = Si[r];
            Sr[r] = cp * xr - sp * xi;
            Si[r] = sp * xr + cp * xi;
        }
    };

    for (int tt = 0; tt < TS; ++tt) {
        float phs[30];
#pragma unroll
        for (int j = 0; j < 30; ++j) phs[j] = ph[30 * tt + j];

        // boundary diagonal: v = a(t) + b(t-1), pair term from step t-1
        float v[NQ];
#pragma unroll
        for (int i = 0; i < NQ; ++i) v[i] = phs[i] + bprev[i];
        apply_diag(v, kk);

        // Ry block: c=cos(th/2), s=sin(th/2)
        float rc[NQ], rs[NQ];
#pragma unroll
        for (int i = 0; i < NQ; ++i) __sincosf(0.5f * phs[10 + i], &rs[i], &rc[i]);

        ry_r<3>(Sr, Si, rc[0], rs[0]);                 // qubit 0 (idx bit 9)
        ry_r<2>(Sr, Si, rc[1], rs[1]);                 // qubit 1 (bit 8)
        ry_r<1>(Sr, Si, rc[2], rs[2]);                 // qubit 2 (bit 7)
        ry_r<0>(Sr, Si, rc[3], rs[3]);                 // qubit 3 (bit 6)
        ry_lane<32>(lane, Sr, Si, rc[4], rs[4]);       // qubit 4 (shfl)
        ry_lane<16>(lane, Sr, Si, rc[5], rs[5]);       // qubit 5 (shfl)
        ry_lane< 8>(lane, Sr, Si, rc[6], rs[6]);       // qubit 6 (DPP)
        ry_lane< 4>(lane, Sr, Si, rc[7], rs[7]);       // qubit 7 (DPP)
        ry_lane< 2>(lane, Sr, Si, rc[8], rs[8]);       // qubit 8 (DPP)
        ry_lane< 1>(lane, Sr, Si, rc[9], rs[9]);       // qubit 9 (DPP)

#pragma unroll
        for (int i = 0; i < NQ; ++i) bprev[i] = phs[20 + i];
        kk = -0.5f * (gsp[tt] * inv);
    }

    // trailing diagonal: b(9) phases + pairsum(9)
    apply_diag(bprev, kk);

    float* outr = out + sample * DIM;
    float* outi = out + ND * DIM + sample * DIM;
#pragma unroll
    for (int r = 0; r < NR; ++r) {
        outr[r * 64 + lane] = Sr[r];
        outi[r * 64 + lane] = Si[r];
    }
}

extern "C" void kernel_launch(void* const* d_in, const int* in_sizes, int n_in,
                              void* d_out, int out_size, void* d_ws, size_t ws_size,
                              hipStream_t stream) {
    const float* re_in = (const float*)d_in[0];
    const float* im_in = (const float*)d_in[1];
    const float* phis  = (const float*)d_in[2];
    const float* gs    = (const float*)d_in[3];
    float* out = (float*)d_out;
    qsim_kernel<<<ND, 64, 0, stream>>>(re_in, im_in, phis, gs, out);
}

// Round 11
// 92.015 us; speedup vs baseline: 1.0980x; 1.0057x over previous
//
#include <hip/hip_runtime.h>

#define NQ 10
#define TS 10
#define DIM 1024
#define ND 1024
#define NR 16    // 16 complex amplitudes per lane (Sr/Si float arrays)

// Circuit algebra (R9-verified): M = Rz(b)·Ry(th)·Rz(a); per-qubit factors
// commute, so each step = [Pi Rz(b)]·[Pi Ry]·[Pi Rz(a)]·D_pair and all
// diagonals merge across step boundaries into ONE diagonal per boundary:
//   phi(idx) = sum_{set bits} v_i - 0.5*sum(v) + k*pairsum(idx),
//   v_i = a_i(t) + b_i(t-1) (b(-1)=0), k = -0.5*theta(t-1) (0 at t=0).
// Ry is a REAL Givens rotation: 2 ops per float per gate.

// ---------- full-rate cross-lane exchange via DPP (verified R5) ----------
template<int CTRL>
__device__ __forceinline__ float dpp_full(float x) {
    const int xi = __float_as_int(x);
    return __int_as_float(__builtin_amdgcn_update_dpp(xi, xi, CTRL, 0xF, 0xF, false));
}
__device__ __forceinline__ float dpp_xor4(float x) {
    const int xi = __float_as_int(x);
    // banks 0,2 (bit2=0) need src[i+4] -> row_shl:4 (0x104), bank_mask 0x5
    // banks 1,3 (bit2=1) need src[i-4] -> row_shr:4 (0x114), bank_mask 0xA
    int q = __builtin_amdgcn_update_dpp(0, xi, 0x104, 0xF, 0x5, false);
    q     = __builtin_amdgcn_update_dpp(q, xi, 0x114, 0xF, 0xA, false);
    return __int_as_float(q);
}
__device__ __forceinline__ float bperm(int addr, float x) {  // addr hoisted
    return __int_as_float(__builtin_amdgcn_ds_bpermute(addr, __float_as_int(x)));
}
template<int MASK>
__device__ __forceinline__ float lshuf(float x, int addr) {
    if constexpr (MASK == 1)      return dpp_full<0xB1>(x);   // quad_perm [1,0,3,2]
    else if constexpr (MASK == 2) return dpp_full<0x4E>(x);   // quad_perm [2,3,0,1]
    else if constexpr (MASK == 4) return dpp_xor4(x);
    else if constexpr (MASK == 8) return dpp_full<0x128>(x);  // row_ror:8 == xor8
    else return bperm(addr, x);                               // 16,32
}

// ---------- Ry gates (real rotation [[c,-s],[s,c]]) ----------
template <int RB>   // pairing on register bit RB
__device__ __forceinline__ void ry_r(float* Sr, float* Si, float c, float s) {
#pragma unroll
    for (int r0 = 0; r0 < NR; ++r0) {
        if (r0 & (1 << RB)) continue;
        const int r1 = r0 | (1 << RB);
        const float x0r = Sr[r0], x1r = Sr[r1];
        const float x0i = Si[r0], x1i = Si[r1];
        Sr[r0] = c * x0r - s * x1r;
        Sr[r1] = s * x0r + c * x1r;
        Si[r0] = c * x0i - s * x1i;
        Si[r1] = s * x0i + c * x1i;
    }
}
template <int MASK> // pairing on lane bit MASK
__device__ __forceinline__ void ry_lane(int lane, int addr, float* Sr, float* Si,
                                        float c, float s) {
    const float ss = (lane & MASK) ? s : -s;  // x' = c*own + ss*partner
    float qr[NR], qi[NR];
#pragma unroll
    for (int r = 0; r < NR; ++r) {
        qr[r] = lshuf<MASK>(Sr[r], addr);
        qi[r] = lshuf<MASK>(Si[r], addr);
    }
#pragma unroll
    for (int r = 0; r < NR; ++r) {
        Sr[r] = c * Sr[r] + ss * qr[r];
        Si[r] = c * Si[r] + ss * qi[r];
    }
}

// One wave per sample, full state in registers, zero LDS.
__global__ __launch_bounds__(64, 1) void qsim_kernel(
    const float* __restrict__ re_in, const float* __restrict__ im_in,
    const float* __restrict__ phis, const float* __restrict__ gs,
    float* __restrict__ out)
{
    const int sample = blockIdx.x;
    const int lane = threadIdx.x;

    const float* pr_in = re_in + sample * DIM;
    const float* pi_in = im_in + sample * DIM;

    float Sr[NR], Si[NR];
#pragma unroll
    for (int r = 0; r < NR; ++r) {
        Sr[r] = pr_in[r * 64 + lane];
        Si[r] = pi_in[r * 64 + lane];
    }

    const int bp16 = (lane ^ 16) << 2;   // hoisted bpermute byte-addresses
    const int bp32 = (lane ^ 32) << 2;

    const float inv = 0.15811388300841897f;  // 1/(2*sqrt(10))
    const float* gsp = gs + sample * TS;

    // ---- normalize ----
    float nrm = 0.f;
#pragma unroll
    for (int r = 0; r < NR; ++r) nrm += Sr[r] * Sr[r] + Si[r] * Si[r];
#pragma unroll
    for (int off = 32; off >= 1; off >>= 1) nrm += __shfl_xor(nrm, off, 64);
    const float scl = rsqrtf(nrm);
#pragma unroll
    for (int r = 0; r < NR; ++r) { Sr[r] *= scl; Si[r] *= scl; }

    // ---- static per-amp pairsum ----
    float ps[NR];
#pragma unroll
    for (int r = 0; r < NR; ++r) {
        const int idx = r * 64 + lane;
        const int z = NQ - 2 * __popc(idx);
        ps[r] = 0.5f * (float)(z * z - NQ);
    }
    // lane-bit indicators for qubits 4..9 (qubit 4+j <-> lane bit 5-j)
    float bl[6];
#pragma unroll
    for (int j = 0; j < 6; ++j) bl[j] = (float)((lane >> (5 - j)) & 1);

    const float* ph = phis + sample * (3 * NQ * TS);

    float bprev[NQ];
#pragma unroll
    for (int i = 0; i < NQ; ++i) bprev[i] = 0.f;
    float kk = 0.f;   // pair-diag coefficient from previous step

    // merged diagonal: phi[r] = HL[r] + kcur*ps[r], rotate state by e^{i*phi}
    auto apply_diag = [&](const float* v, float kcur) {
        float sv = 0.f;
#pragma unroll
        for (int i = 0; i < NQ; ++i) sv += v[i];
        float wl = 0.f;
#pragma unroll
        for (int j = 0; j < 6; ++j) wl = fmaf(bl[j], v[4 + j], wl);
        const float m = fmaf(-0.5f, sv, wl);
        // r bit3<->v0, bit2<->v1, bit1<->v2, bit0<->v3
        const float Hm[4] = {m, m + v[1], m + v[0], m + v[0] + v[1]};
        const float L[4]  = {0.f, v[3], v[2], v[2] + v[3]};
        float HL[NR];
#pragma unroll
        for (int r = 0; r < NR; ++r) HL[r] = Hm[r >> 2] + L[r & 3];
#pragma unroll
        for (int r = 0; r < NR; ++r) {
            const float phi = fmaf(kcur, ps[r], HL[r]);
            const float sp = __sinf(phi);
            const float cp = __cosf(phi);
            const float xr = Sr[r], xi = Si[r];
            Sr[r] = cp * xr - sp * xi;
            Si[r] = sp * xr + cp * xi;
        }
    };

    for (int tt = 0; tt < TS; ++tt) {
        float phs[30];
#pragma unroll
        for (int j = 0; j < 30; ++j) phs[j] = ph[30 * tt + j];

        // boundary diagonal: v = a(t) + b(t-1), pair term from step t-1
        float v[NQ];
#pragma unroll
        for (int i = 0; i < NQ; ++i) v[i] = phs[i] + bprev[i];
        apply_diag(v, kk);

        // Ry block: c=cos(th/2), s=sin(th/2)  (native trans, angles small)
        float rc[NQ], rs[NQ];
#pragma unroll
        for (int i = 0; i < NQ; ++i) {
            const float h = 0.5f * phs[10 + i];
            rs[i] = __sinf(h);
            rc[i] = __cosf(h);
        }

        ry_r<3>(Sr, Si, rc[0], rs[0]);                    // qubit 0 (idx bit 9)
        ry_r<2>(Sr, Si, rc[1], rs[1]);                    // qubit 1 (bit 8)
        ry_r<1>(Sr, Si, rc[2], rs[2]);                    // qubit 2 (bit 7)
        ry_r<0>(Sr, Si, rc[3], rs[3]);                    // qubit 3 (bit 6)
        ry_lane<32>(lane, bp32, Sr, Si, rc[4], rs[4]);    // qubit 4 (bperm)
        ry_lane<16>(lane, bp16, Sr, Si, rc[5], rs[5]);    // qubit 5 (bperm)
        ry_lane< 8>(lane, 0,    Sr, Si, rc[6], rs[6]);    // qubit 6 (DPP)
        ry_lane< 4>(lane, 0,    Sr, Si, rc[7], rs[7]);    // qubit 7 (DPP)
        ry_lane< 2>(lane, 0,    Sr, Si, rc[8], rs[8]);    // qubit 8 (DPP)
        ry_lane< 1>(lane, 0,    Sr, Si, rc[9], rs[9]);    // qubit 9 (DPP)

#pragma unroll
        for (int i = 0; i < NQ; ++i) bprev[i] = phs[20 + i];
        kk = -0.5f * (gsp[tt] * inv);
    }

    // trailing diagonal: b(9) phases + pairsum(9)
    apply_diag(bprev, kk);

    float* outr = out + sample * DIM;
    float* outi = out + ND * DIM + sample * DIM;
#pragma unroll
    for (int r = 0; r < NR; ++r) {
        outr[r * 64 + lane] = Sr[r];
        outi[r * 64 + lane] = Si[r];
    }
}

extern "C" void kernel_launch(void* const* d_in, const int* in_sizes, int n_in,
                              void* d_out, int out_size, void* d_ws, size_t ws_size,
                              hipStream_t stream) {
    const float* re_in = (const float*)d_in[0];
    const float* im_in = (const float*)d_in[1];
    const float* phis  = (const float*)d_in[2];
    const float* gs    = (const float*)d_in[3];
    float* out = (float*)d_out;
    qsim_kernel<<<ND, 64, 0, stream>>>(re_in, im_in, phis, gs, out);
}